// Round 3
// baseline (182.821 us; speedup 1.0000x reference)
//
#include <hip/hip_runtime.h>
#include <hip/hip_bf16.h>

#define BATCH 16384
#define IN_F 512
#define OUT_F 512
#define NG 8
#define KTOT (IN_F * NG)   // 4096

// basis_j(x) = exp(-((x-g_j)/h)^2) = 2^(-t_j^2), t_j = t0 - j*s,
//   t0 = SH*x + BC0N, s = SSTEP = sqrt(log2 e) => s^2 = log2 e, 2^(-s^2) = 1/e.
// Separable: basis_j = v0 * rho^j * e^(-j^2), v0 = 2^(-t0^2),
//   rho = exp2(RC1*t0); x-independent e^(-j^2) folded into Wt (QS[]).
#define SH    2.1019642153762872f
#define SSTEP 1.2011224087864498f
#define BC0N  4.2039284307525745f
#define RC1   2.4022448175728996f    // 2s

typedef __attribute__((ext_vector_type(8))) short short8;
typedef __attribute__((ext_vector_type(4))) float f32x4;
typedef __attribute__((ext_vector_type(2))) float f32x2;
typedef __attribute__((ext_vector_type(4))) unsigned int u32x4;
typedef __attribute__((ext_vector_type(2))) unsigned int u32x2;

__device__ __forceinline__ unsigned fbits(float f) {
    union { float f; unsigned u; } v; v.f = f; return v.u;
}
// (lo>>16)|(hi&0xFFFF0000) with rne adds, single v_perm_b32.
__device__ __forceinline__ unsigned pack2bf(float lo, float hi) {
    return __builtin_amdgcn_perm(fbits(hi) + 0x8000u, fbits(lo) + 0x8000u,
                                 0x07060302u);
}

// Full A-fragment (8 grid basis values, bf16-packed) from ONE x scalar.
// Numerically verified (R8 passed absmax=0.0625 with this chain + QS-folded Wt).
__device__ __forceinline__ short8 basis_frag(float x) {
    const float t0  = fmaf(x, SH, BC0N);
    const float rho = __builtin_amdgcn_exp2f(t0 * RC1);
    const float v0  = __builtin_amdgcn_exp2f(-t0 * t0);
    const float v1 = v0 * rho;
    const float v2 = v1 * rho;
    const float v3 = v2 * rho;
    const float v4 = v3 * rho;
    const float v5 = v4 * rho;
    const float v6 = v5 * rho;
    const float v7 = v6 * rho;
    u32x4 pk;
    pk[0] = pack2bf(v0, v1);
    pk[1] = pack2bf(v2, v3);
    pk[2] = pack2bf(v4, v5);
    pk[3] = pack2bf(v6, v7);
    union { u32x4 u; short8 s; } cv; cv.u = pk;
    return cv.s;
}

// lgkm-only barrier (used by gemm9 fallback path).
__device__ __forceinline__ void lds_barrier() {
    __asm__ volatile("" ::: "memory");
    __builtin_amdgcn_sched_barrier(0);
    __builtin_amdgcn_s_waitcnt(0xC07F);
    __builtin_amdgcn_s_barrier();
    __builtin_amdgcn_sched_barrier(0);
    __asm__ volatile("" ::: "memory");
}

// ---- combined prep: Wt swizzle (blocks 0..1023) + XtF swizzle (1024..5119) ----
// Wt layout (as before): for s,kt,f=kk*4+j,lane:
//   Wt[ (((s*64+kt)*8+f)*64 + lane)*8 + e ] =
//     W[ kt*64 + kk*32 + (lane>>4)*8 + e ][ s*64 + j*16 + (lane&15) ] * e^(-g^2)
// XtF layout: frag-major f32 so a GEMM lane's 8 per-iter x-scalars are contiguous:
//   XtF[ (((rb*64 + kt)*64 + lane)*8) + e ],  e = kk*4 + i,
//     = X[ rb*64 + i*16 + (lane&15) ][ kt*8 + kk*4 + (lane>>4) ]
__global__ void prep_all(const float* __restrict__ W, const float* __restrict__ X,
                         unsigned short* __restrict__ Wt, float* __restrict__ XtF) {
    const int tid = threadIdx.x;
    if (blockIdx.x < 1024) {
        const int gid  = blockIdx.x * 256 + tid;   // 0..262143
        const int lane = gid & 63;
        const int f    = (gid >> 6) & 7;
        const int kt   = (gid >> 9) & 63;
        const int s    = gid >> 15;
        const int j  = f & 3, kk = f >> 2;
        const int l15 = lane & 15, lq = lane >> 4;
        const int n  = s * 64 + j * 16 + l15;
        const int k0 = kt * 64 + kk * 32 + lq * 8;
        constexpr float QS[8] = {1.0f,
                                 3.6787944117144233e-1f,   // e^-1
                                 1.8315638888734179e-2f,   // e^-4
                                 1.2340980408667956e-4f,   // e^-9
                                 1.1253517471925912e-7f,   // e^-16
                                 1.3887943864964021e-11f,  // e^-25
                                 2.3195228302435693e-16f,  // e^-36
                                 5.2428856633634640e-22f}; // e^-49
        u32x4 pk;
#pragma unroll
        for (int e = 0; e < 4; ++e)
            pk[e] = pack2bf(W[(size_t)(k0 + 2 * e) * OUT_F + n] * QS[2 * e],
                            W[(size_t)(k0 + 2 * e + 1) * OUT_F + n] * QS[2 * e + 1]);
        *(u32x4*)(Wt + (size_t)gid * 8) = pk;
    } else {
        const int bid2 = blockIdx.x - 1024;        // 0..4095
        const int rb   = bid2 >> 4;                // 0..255
        const int ktq  = bid2 & 15;                // 0..15
        const int ktl  = tid >> 6;                 // 0..3
        const int lane = tid & 63;
        const int kt   = ktq * 4 + ktl;            // 0..63
        const int l15 = lane & 15, lq = lane >> 4;
        float v[8];
#pragma unroll
        for (int e = 0; e < 8; ++e) {
            const int i  = e & 3, kk = e >> 2;
            const int m  = rb * 64 + i * 16 + l15;
            const int c  = kt * 8 + kk * 4 + lq;
            v[e] = X[(size_t)m * IN_F + c];
        }
        float* dst = XtF + ((size_t)(rb * 64 + kt) * 64 + lane) * 8;
        *(f32x4*)(dst)     = (f32x4){v[0], v[1], v[2], v[3]};
        *(f32x4*)(dst + 4) = (f32x4){v[4], v[5], v[6], v[7]};
    }
}

// ================= R10: barrier-free, LDS-free, coalesced frag-major A =======
// 256 thr (4 waves), block 64m x 256n, wave = 64m x 64n, grid 512.
// Per iter per wave: 2 coalesced A-loads (dwordx4, frag-major XtF), 8 B-loads
// (dwordx4, frag-major Wt), 8 in-register basis chains, 32 MFMA. No LDS, no
// barriers: free-running waves anti-phase so one wave's basis VALU overlaps
// the co-resident wave's MFMA burst (m114). A/B reg-prefetched 1 iter ahead.
__global__ __launch_bounds__(256, 2) void gauss_gemm10(
        const float* __restrict__ XtF, const unsigned short* __restrict__ Wt,
        float* __restrict__ Out) {
    const int tid  = threadIdx.x;
    const int lane = tid & 63;
    const int wave = tid >> 6;
    // XCD-chunked bijective swizzle (keep: harmless, mild L2 locality).
    const int nb = (blockIdx.x & 7) * 64 + (blockIdx.x >> 3);
    const int cb = nb >> 8;          // 0..1
    const int rb = nb & 255;         // 0..255
    const int m0 = rb * 64;
    const int n0 = cb * 256;
    const int l15 = lane & 15;
    const int lq  = lane >> 4;
    const int s   = cb * 4 + wave;   // global n-slice for this wave

    // B source: frag f at tile kt -> bptr + kt*4096 + f*512 (elems)
    const unsigned short* bptr = Wt + (size_t)s * 262144 + lane * 8;
    // A source: iter kt -> aptr + kt*512 (f32), 32B contiguous per lane
    const float* aptr = XtF + (size_t)rb * 32768 + (size_t)lane * 8;

    f32x4 acc[4][4];
#pragma unroll
    for (int i = 0; i < 4; ++i)
#pragma unroll
        for (int j = 0; j < 4; ++j)
            acc[i][j] = (f32x4){0.f, 0.f, 0.f, 0.f};

    short8 bfA[8], bfB[8];
    f32x4 xaA0, xaA1, xaB0, xaB1;    // A prefetch regs (named: no dyn indexing)

    // ---- prologue: A(0)->xaA, B(0)->bfA ----
    xaA0 = *(const f32x4*)(aptr);
    xaA1 = *(const f32x4*)(aptr + 4);
#pragma unroll
    for (int f = 0; f < 8; ++f)
        bfA[f] = *(const short8*)(bptr + f * 512);

// Iter: issue next A+B loads (latency hides under this iter's VALU+MFMA),
// build af from prefetched x, MFMA cluster under setprio. No sync at all.
#define GG_ITER(KT, BU, BF, XU0, XU1, XF0, XF1)                                \
    {                                                                          \
        const int kn1 = ((KT) + 1 < 63) ? (KT) + 1 : 63;                       \
        XF0 = *(const f32x4*)(aptr + kn1 * 512);                               \
        XF1 = *(const f32x4*)(aptr + kn1 * 512 + 4);                           \
        _Pragma("unroll")                                                      \
        for (int f = 0; f < 8; ++f)                                            \
            BF[f] = *(const short8*)(bptr + (size_t)kn1 * 4096 + f * 512);     \
        short8 af[2][4];                                                       \
        _Pragma("unroll")                                                      \
        for (int i = 0; i < 4; ++i)                                            \
            af[0][i] = basis_frag(XU0[i]);                                     \
        _Pragma("unroll")                                                      \
        for (int i = 0; i < 4; ++i)                                            \
            af[1][i] = basis_frag(XU1[i]);                                     \
        __builtin_amdgcn_s_setprio(1);                                         \
        _Pragma("unroll")                                                      \
        for (int kk = 0; kk < 2; ++kk)                                         \
            _Pragma("unroll")                                                  \
            for (int i = 0; i < 4; ++i)                                        \
                _Pragma("unroll")                                              \
                for (int j = 0; j < 4; ++j)                                    \
                    acc[i][j] = __builtin_amdgcn_mfma_f32_16x16x32_bf16(       \
                        af[kk][i], BU[kk * 4 + j], acc[i][j], 0, 0, 0);        \
        __builtin_amdgcn_s_setprio(0);                                         \
    }

    for (int kt = 0; kt < 64; kt += 2) {
        GG_ITER(kt,     bfA, bfB, xaA0, xaA1, xaB0, xaB1)
        GG_ITER(kt + 1, bfB, bfA, xaB0, xaB1, xaA0, xaA1)
    }
#undef GG_ITER

    // ---- epilogue: C/D layout col=lane&15, row=(lane>>4)*4+e ----
#pragma unroll
    for (int i = 0; i < 4; ++i) {
        const int r0 = m0 + i * 16 + lq * 4;
#pragma unroll
        for (int j = 0; j < 4; ++j) {
            const int c = n0 + wave * 64 + j * 16 + l15;
#pragma unroll
            for (int e = 0; e < 4; ++e)
                Out[(size_t)(r0 + e) * OUT_F + c] = acc[i][j][e];
        }
    }
}

// ---- standalone Wt swizzle (mid-tier fallback path) ----
__global__ void wt_swizzle(const float* __restrict__ W, unsigned short* __restrict__ Wt) {
    const int gid  = blockIdx.x * 256 + threadIdx.x;
    const int lane = gid & 63;
    const int f    = (gid >> 6) & 7;
    const int kt   = (gid >> 9) & 63;
    const int s    = gid >> 15;
    const int j  = f & 3, kk = f >> 2;
    const int l15 = lane & 15, lq = lane >> 4;
    const int n  = s * 64 + j * 16 + l15;
    const int k0 = kt * 64 + kk * 32 + lq * 8;
    constexpr float QS[8] = {1.0f,
                             3.6787944117144233e-1f,
                             1.8315638888734179e-2f,
                             1.2340980408667956e-4f,
                             1.1253517471925912e-7f,
                             1.3887943864964021e-11f,
                             2.3195228302435693e-16f,
                             5.2428856633634640e-22f};
    u32x4 pk;
#pragma unroll
    for (int e = 0; e < 4; ++e)
        pk[e] = pack2bf(W[(size_t)(k0 + 2 * e) * OUT_F + n] * QS[2 * e],
                        W[(size_t)(k0 + 2 * e + 1) * OUT_F + n] * QS[2 * e + 1]);
    *(u32x4*)(Wt + (size_t)gid * 8) = pk;
}

// ================= R9 (mid-tier fallback: ws fits Wt but not XtF) ============
__global__ __launch_bounds__(256, 2) void gauss_gemm9(
        const float* __restrict__ X, const unsigned short* __restrict__ Wt,
        float* __restrict__ Out) {
    __shared__ __align__(16) unsigned short sA[2 * 64 * 64];

    const int tid  = threadIdx.x;
    const int lane = tid & 63;
    const int wave = tid >> 6;
    const int nb = (blockIdx.x & 7) * 64 + (blockIdx.x >> 3);
    const int cb = nb >> 8;
    const int rb = nb & 255;
    const int m0 = rb * 64;
    const int n0 = cb * 256;
    const int l15 = lane & 15;
    const int lq  = lane >> 4;
    const int s   = cb * 4 + wave;

    const int aw0 = lane * 64 + (((2 * wave)     ^ (lane & 7)) << 3);
    const int aw1 = lane * 64 + (((2 * wave + 1) ^ (lane & 7)) << 3);
    const float* xlp = X + (size_t)(m0 + lane) * IN_F + wave * 2;

    int aofs[2][4];
#pragma unroll
    for (int kk = 0; kk < 2; ++kk)
#pragma unroll
        for (int i = 0; i < 4; ++i)
            aofs[kk][i] = (i * 16 + l15) * 64 + (((kk * 4 + lq) ^ (l15 & 7)) << 3);

    const unsigned short* bptr = Wt + (size_t)s * 262144 + lane * 8;

    f32x4 acc[4][4];
#pragma unroll
    for (int i = 0; i < 4; ++i)
#pragma unroll
        for (int j = 0; j < 4; ++j)
            acc[i][j] = (f32x4){0.f, 0.f, 0.f, 0.f};

    auto stageA = [&](f32x2 xv, int buf) {
        unsigned short* base = sA + buf * 4096;
#pragma unroll
        for (int h = 0; h < 2; ++h) {
            const float t0  = fmaf(h ? xv.y : xv.x, SH, BC0N);
            const float rho = __builtin_amdgcn_exp2f(t0 * RC1);
            const float v0  = __builtin_amdgcn_exp2f(-t0 * t0);
            const float v1 = v0 * rho;
            const float v2 = v1 * rho;
            const float v3 = v2 * rho;
            const float v4 = v3 * rho;
            const float v5 = v4 * rho;
            const float v6 = v5 * rho;
            const float v7 = v6 * rho;
            u32x4 pk;
            pk[0] = pack2bf(v0, v1);
            pk[1] = pack2bf(v2, v3);
            pk[2] = pack2bf(v4, v5);
            pk[3] = pack2bf(v6, v7);
            *(u32x4*)(base + (h ? aw1 : aw0)) = pk;
        }
    };

    short8 bfA[8], bfB[8];
    f32x2 xr;

    {
        f32x2 x0 = *(const f32x2*)(xlp);
        stageA(x0, 0);
#pragma unroll
        for (int f = 0; f < 8; ++f)
            bfA[f] = *(const short8*)(bptr + f * 512);
        xr = *(const f32x2*)(xlp + 8);
        lds_barrier();
    }

#define GG_ITER9(KT, BUF, BU, BF)                                              \
    {                                                                          \
        const int kn1 = ((KT) + 1 < 63) ? (KT) + 1 : 63;                       \
        const int kn2 = ((KT) + 2 < 63) ? (KT) + 2 : 63;                       \
        _Pragma("unroll")                                                      \
        for (int f = 0; f < 8; ++f)                                            \
            BF[f] = *(const short8*)(bptr + (size_t)kn1 * 4096 + f * 512);     \
        short8 af[2][4];                                                       \
        _Pragma("unroll")                                                      \
        for (int kk = 0; kk < 2; ++kk)                                         \
            _Pragma("unroll")                                                  \
            for (int i = 0; i < 4; ++i)                                        \
                af[kk][i] = *(const short8*)(sA + (BUF) * 4096 + aofs[kk][i]); \
        f32x2 xn = *(const f32x2*)(xlp + (size_t)kn2 * 8);                     \
        stageA(xr, (BUF) ^ 1);                                                 \
        xr = xn;                                                               \
        __builtin_amdgcn_s_setprio(1);                                         \
        _Pragma("unroll")                                                      \
        for (int kk = 0; kk < 2; ++kk)                                         \
            _Pragma("unroll")                                                  \
            for (int i = 0; i < 4; ++i)                                        \
                _Pragma("unroll")                                              \
                for (int j = 0; j < 4; ++j)                                    \
                    acc[i][j] = __builtin_amdgcn_mfma_f32_16x16x32_bf16(       \
                        af[kk][i], BU[kk * 4 + j], acc[i][j], 0, 0, 0);        \
        __builtin_amdgcn_s_setprio(0);                                         \
        lds_barrier();                                                         \
    }

    for (int kt = 0; kt < 64; kt += 2) {
        GG_ITER9(kt,     0, bfA, bfB)
        GG_ITER9(kt + 1, 1, bfB, bfA)
    }
#undef GG_ITER9

#pragma unroll
    for (int i = 0; i < 4; ++i) {
        const int r0 = m0 + i * 16 + lq * 4;
#pragma unroll
        for (int j = 0; j < 4; ++j) {
            const int c = n0 + wave * 64 + j * 16 + l15;
#pragma unroll
            for (int e = 0; e < 4; ++e)
                Out[(size_t)(r0 + e) * OUT_F + c] = acc[i][j][e];
        }
    }
}

// ================= fallback (ws too small for Wt) =================
#define BM 128
#define BN 128
#define BK 64
#define LDA 72
#define LDB 72

__global__ __launch_bounds__(256, 2) void gauss_gemm_fb(
        const float* __restrict__ X, const float* __restrict__ W,
        float* __restrict__ Out) {
    __shared__ __align__(16) unsigned short sA[BM * LDA];
    __shared__ __align__(16) unsigned short sB2[BN * LDB];

    const int tid  = threadIdx.x;
    const int lane = tid & 63;
    const int wave = tid >> 6;
    const int rb = blockIdx.x >> 2;
    const int cbx = blockIdx.x & 3;
    const int m0 = rb * BM;
    const int n0 = cbx * BN;
    const int wr = (wave >> 1) * 64;
    const int wc = (wave & 1) * 64;
    const int l15 = lane & 15;
    const int lq  = lane >> 4;

    f32x4 acc[4][4];
#pragma unroll
    for (int i = 0; i < 4; ++i)
#pragma unroll
        for (int j = 0; j < 4; ++j)
            acc[i][j] = (f32x4){0.f, 0.f, 0.f, 0.f};

    const int arow = tid & 127;
    const int axq  = tid >> 7;

    for (int kt = 0; kt < KTOT / BK; ++kt) {
        const int k0  = kt * BK;
        const int xc0 = kt * (BK / NG);

        const f32x4 xv = *(const f32x4*)(X + (size_t)(m0 + arow) * IN_F + xc0 + 4 * axq);
        unsigned short* sArow = sA + arow * LDA + axq * 32;
#pragma unroll
        for (int j = 0; j < 4; ++j) {
            const float xs = xv[j] * SH;
            u32x4 pk;
#pragma unroll
            for (int g = 0; g < 8; g += 2) {
                float t0 = xs + (BC0N - g * SSTEP);
                float t1 = xs + (BC0N - (g + 1) * SSTEP);
                pk[g >> 1] = pack2bf(__builtin_amdgcn_exp2f(-t0 * t0),
                                     __builtin_amdgcn_exp2f(-t1 * t1));
            }
            *(u32x4*)(sArow + j * 8) = pk;
        }

#pragma unroll
        for (int p = 0; p < 8; ++p) {
            int id = p * 256 + tid;
            int n  = id & 127;
            int k4 = id >> 7;
            const float* wp = W + (size_t)(k0 + k4 * 4) * OUT_F + n0 + n;
            u32x2 v;
            v[0] = pack2bf(wp[0], wp[OUT_F]);
            v[1] = pack2bf(wp[2 * OUT_F], wp[3 * OUT_F]);
            *(u32x2*)(sB2 + n * LDB + k4 * 4) = v;
        }

        __syncthreads();

#pragma unroll
        for (int kk = 0; kk < BK; kk += 32) {
            short8 af[4], bfv[4];
#pragma unroll
            for (int i = 0; i < 4; ++i)
                af[i] = *(const short8*)(sA + (wr + i * 16 + l15) * LDA + kk + lq * 8);
#pragma unroll
            for (int i = 0; i < 4; ++i)
                bfv[i] = *(const short8*)(sB2 + (wc + i * 16 + l15) * LDB + kk + lq * 8);
#pragma unroll
            for (int i = 0; i < 4; ++i)
#pragma unroll
                for (int j = 0; j < 4; ++j)
                    acc[i][j] = __builtin_amdgcn_mfma_f32_16x16x32_bf16(af[i], bfv[j], acc[i][j], 0, 0, 0);
        }

        __syncthreads();
    }

#pragma unroll
    for (int i = 0; i < 4; ++i) {
        const int r0 = m0 + wr + i * 16 + lq * 4;
#pragma unroll
        for (int j = 0; j < 4; ++j) {
            const int c = n0 + wc + j * 16 + l15;
#pragma unroll
            for (int e = 0; e < 4; ++e)
                Out[(size_t)(r0 + e) * OUT_F + c] = acc[i][j][e];
        }
    }
}

extern "C" void kernel_launch(void* const* d_in, const int* in_sizes, int n_in,
                              void* d_out, int out_size, void* d_ws, size_t ws_size,
                              hipStream_t stream) {
    (void)in_sizes; (void)n_in; (void)out_size;
    const float* X = (const float*)d_in[0];
    // d_in[1] = grid (constants hardcoded: linspace(-2,2,8))
    const float* W = (const float*)d_in[2];
    float* Out = (float*)d_out;

    const size_t wt_bytes  = (size_t)KTOT * OUT_F * sizeof(unsigned short);  // 4 MB
    const size_t xtf_bytes = (size_t)BATCH * IN_F * sizeof(float);           // 32 MB
    if (ws_size >= wt_bytes + xtf_bytes) {
        unsigned short* Wt = (unsigned short*)d_ws;
        float* XtF = (float*)((char*)d_ws + wt_bytes);
        prep_all<<<dim3(1024 + 4096), 256, 0, stream>>>(W, X, Wt, XtF);
        gauss_gemm10<<<dim3((BATCH / 64) * (OUT_F / 256)), 256, 0, stream>>>(XtF, Wt, Out);
    } else if (ws_size >= wt_bytes) {
        unsigned short* Wt = (unsigned short*)d_ws;
        wt_swizzle<<<dim3(KTOT * OUT_F / 8 / 256), 256, 0, stream>>>(W, Wt);
        gauss_gemm9<<<dim3((BATCH / 64) * (OUT_F / 256)), 256, 0, stream>>>(X, Wt, Out);
    } else {
        gauss_gemm_fb<<<dim3((BATCH / BM) * (OUT_F / BN)), 256, 0, stream>>>(X, W, Out);
    }
}

// Round 4
// 149.334 us; speedup vs baseline: 1.2242x; 1.2242x over previous
//
#include <hip/hip_runtime.h>
#include <hip/hip_bf16.h>

#define BATCH 16384
#define IN_F 512
#define OUT_F 512
#define NG 8
#define KTOT (IN_F * NG)   // 4096

// basis_j(x) = exp(-((x-g_j)/h)^2) = 2^(-t_j^2), t_j = t0 - j*s,
//   t0 = SH*x + BC0N, s = SSTEP = sqrt(log2 e) => s^2 = log2 e, 2^(-s^2) = 1/e.
// Separable: basis_j = v0 * rho^j * e^(-j^2), v0 = 2^(-t0^2),
//   rho = exp2(RC1*t0); x-independent e^(-j^2) folded into Wt (QS[]).
#define SH    2.1019642153762872f
#define SSTEP 1.2011224087864498f
#define BC0N  4.2039284307525745f
#define RC1   2.4022448175728996f    // 2s

typedef __attribute__((ext_vector_type(8))) short short8;
typedef __attribute__((ext_vector_type(4))) float f32x4;
typedef __attribute__((ext_vector_type(2))) float f32x2;
typedef __attribute__((ext_vector_type(4))) unsigned int u32x4;
typedef __attribute__((ext_vector_type(2))) unsigned int u32x2;

__device__ __forceinline__ unsigned fbits(float f) {
    union { float f; unsigned u; } v; v.f = f; return v.u;
}
// (lo>>16)|(hi&0xFFFF0000) with rne adds, single v_perm_b32.
__device__ __forceinline__ unsigned pack2bf(float lo, float hi) {
    return __builtin_amdgcn_perm(fbits(hi) + 0x8000u, fbits(lo) + 0x8000u,
                                 0x07060302u);
}
// Two f32 -> packed 2xbf16 in ONE instruction (lo in bits 0..15).
__device__ __forceinline__ unsigned cvtpk(float lo, float hi) {
    unsigned r;
    asm("v_cvt_pk_bf16_f32 %0, %1, %2" : "=v"(r) : "v"(lo), "v"(hi));
    return r;
}

// lgkm-only barrier: per-wave lgkmcnt(0) (LDS ops visible) then raw s_barrier.
// B/X register prefetch (vmcnt) survives across it. 0xC07F = vmcnt(63)
// expcnt(7) lgkmcnt(0).
__device__ __forceinline__ void lds_barrier() {
    __asm__ volatile("" ::: "memory");
    __builtin_amdgcn_sched_barrier(0);
    __builtin_amdgcn_s_waitcnt(0xC07F);
    __builtin_amdgcn_s_barrier();
    __builtin_amdgcn_sched_barrier(0);
    __asm__ volatile("" ::: "memory");
}

// ---- prep: W [KTOT][OUT_F] f32 -> Wt_sw bf16 in MFMA-frag-major layout ----
// For s(0..7: n-slice of 64), kt(0..63), f=kk*4+j (0..7), lane(0..63):
//   Wt_sw[ (((s*64+kt)*8+f)*64 + lane)*8 + e ] =
//     W[ kt*64 + kk*32 + (lane>>4)*8 + e ][ s*64 + j*16 + (lane&15) ] * e^(-g^2)
// g = k mod 8 = within-frag element index (k0 is 8-aligned).
// One wave B-frag = one coalesced 1KB dwordx4 load.
__global__ void wt_swizzle(const float* __restrict__ W, unsigned short* __restrict__ Wt) {
    const int gid  = blockIdx.x * 256 + threadIdx.x;   // 0..262143
    const int lane = gid & 63;
    const int f    = (gid >> 6) & 7;
    const int kt   = (gid >> 9) & 63;
    const int s    = gid >> 15;
    const int j  = f & 3, kk = f >> 2;
    const int l15 = lane & 15, lq = lane >> 4;
    const int n  = s * 64 + j * 16 + l15;
    const int k0 = kt * 64 + kk * 32 + lq * 8;
    constexpr float QS[8] = {1.0f,
                             3.6787944117144233e-1f,   // e^-1
                             1.8315638888734179e-2f,   // e^-4
                             1.2340980408667956e-4f,   // e^-9
                             1.1253517471925912e-7f,   // e^-16
                             1.3887943864964021e-11f,  // e^-25
                             2.3195228302435693e-16f,  // e^-36
                             5.2428856633634640e-22f}; // e^-49
    u32x4 pk;
#pragma unroll
    for (int e = 0; e < 4; ++e)
        pk[e] = pack2bf(W[(size_t)(k0 + 2 * e) * OUT_F + n] * QS[2 * e],
                        W[(size_t)(k0 + 2 * e + 1) * OUT_F + n] * QS[2 * e + 1]);
    *(u32x4*)(Wt + (size_t)gid * 8) = pk;
}

// ================= R12: R9 + 8-slot LDS ring, barrier every 4 iters ==========
// 256 thr (4 waves), block 64m x 256n, BK=64, grid 512 (256 rb x 2 cb).
// A staged 4 K-tiles ahead into an 8-slot (64 KB) frag-major LDS ring;
// lgkm-light barrier only after every 4th iter. Race ledger: iter kt reads
// slot kt&7, writes slot (kt+4)&7; skew < 4 (barrier) => write-slot is in
// read-slot+{1..7} mod 8 — never the read slot; each write->read (dist 4)
// has exactly one barrier between. Between barriers the 4 waves free-run,
// so one wave's basis-VALU overlaps another's MFMA burst (m114, T5).
__global__ __launch_bounds__(256, 2) void gauss_gemm12(
        const float* __restrict__ X, const unsigned short* __restrict__ Wt,
        float* __restrict__ Out) {
    __shared__ __align__(16) unsigned short sA[8 * 4096];   // 64 KB ring

    const int tid  = threadIdx.x;
    const int lane = tid & 63;
    const int wave = tid >> 6;
    // XCD-chunked bijective swizzle (512 blocks, 64/XCD).
    const int nb = (blockIdx.x & 7) * 64 + (blockIdx.x >> 3);
    const int cb = nb >> 8;          // 0..1
    const int rb = nb & 255;         // 0..255
    const int m0 = rb * 64;
    const int n0 = cb * 256;
    const int l15 = lane & 15;
    const int lq  = lane >> 4;
    const int s   = cb * 4 + wave;   // global n-slice for this wave

    // A staging: thread -> row = lane, x-col pair = wave; chunks 2w, 2w+1
    const int aw0 = lane * 64 + (((2 * wave)     ^ (lane & 7)) << 3);
    const int aw1 = lane * 64 + (((2 * wave + 1) ^ (lane & 7)) << 3);
    const float* xlp = X + (size_t)(m0 + lane) * IN_F + wave * 2;

    // A frag read offsets: row i*16+l15, slot (kk*4+lq)^(l15&7)
    int aofs[2][4];
#pragma unroll
    for (int kk = 0; kk < 2; ++kk)
#pragma unroll
        for (int i = 0; i < 4; ++i)
            aofs[kk][i] = (i * 16 + l15) * 64 + (((kk * 4 + lq) ^ (l15 & 7)) << 3);

    // B source: frag f at tile kt -> bptr + kt*4096 + f*512 (elems)
    const unsigned short* bptr = Wt + (size_t)s * 262144 + lane * 8;

    f32x4 acc[4][4];
#pragma unroll
    for (int i = 0; i < 4; ++i)
#pragma unroll
        for (int j = 0; j < 4; ++j)
            acc[i][j] = (f32x4){0.f, 0.f, 0.f, 0.f};

    // QS-folded chain: v_j = v0 * rho^j (e^{-j^2} factors live in Wt).
    // Range: rho <= 2^39, v0*rho^j <= 2^70 -> no overflow; underflow -> 0 ok.
    auto stageA = [&](f32x2 xv, int slot) {
        unsigned short* base = sA + slot * 4096;
#pragma unroll
        for (int h = 0; h < 2; ++h) {
            const float t0  = fmaf(h ? xv.y : xv.x, SH, BC0N);
            const float rho = __builtin_amdgcn_exp2f(t0 * RC1);
            const float v0  = __builtin_amdgcn_exp2f(-t0 * t0);
            const float v1 = v0 * rho;
            const float v2 = v1 * rho;
            const float v3 = v2 * rho;
            const float v4 = v3 * rho;
            const float v5 = v4 * rho;
            const float v6 = v5 * rho;
            const float v7 = v6 * rho;
            u32x4 pk;
            pk[0] = cvtpk(v0, v1);
            pk[1] = cvtpk(v2, v3);
            pk[2] = cvtpk(v4, v5);
            pk[3] = cvtpk(v6, v7);
            *(u32x4*)(base + (h ? aw1 : aw0)) = pk;
        }
    };

    short8 bfA[8], bfB[8];
    f32x2 xu, xv;   // x prefetch ping-pong (distance 2 iters)

    // ---- prologue: stage tiles 0..3 into slots 0..3; xu=x(4), xv=x(5);
    //      bfA = B(0); one barrier. ----
    {
        f32x2 x0 = *(const f32x2*)(xlp);
        f32x2 x1 = *(const f32x2*)(xlp + 8);
        f32x2 x2 = *(const f32x2*)(xlp + 16);
        f32x2 x3 = *(const f32x2*)(xlp + 24);
        xu = *(const f32x2*)(xlp + 32);
        xv = *(const f32x2*)(xlp + 40);
#pragma unroll
        for (int f = 0; f < 8; ++f)
            bfA[f] = *(const short8*)(bptr + f * 512);
        stageA(x0, 0);
        stageA(x1, 1);
        stageA(x2, 2);
        stageA(x3, 3);
        lds_barrier();
    }

// Sub-iter S (0..7): B prefetch kt+1, A-frags from slot S, stage tile kt+4
// into slot (S+4)&7 using XUSE (=x(kt+4), loaded 2 iters ago), reload XUSE
// with x(kt+6), MFMA cluster under setprio. Barrier only when S&3==3.
#define GG12(KT0, S, BU, BF, XUSE)                                             \
    {                                                                          \
        const int kt  = (KT0) + (S);                                           \
        const int kn1 = (kt + 1 < 64) ? kt + 1 : 63;                           \
        const int kn6 = (kt + 6 < 64) ? kt + 6 : 63;                           \
        _Pragma("unroll")                                                      \
        for (int f = 0; f < 8; ++f)                                            \
            BF[f] = *(const short8*)(bptr + (size_t)kn1 * 4096 + f * 512);     \
        short8 af[2][4];                                                       \
        _Pragma("unroll")                                                      \
        for (int kk = 0; kk < 2; ++kk)                                         \
            _Pragma("unroll")                                                  \
            for (int i = 0; i < 4; ++i)                                        \
                af[kk][i] = *(const short8*)(sA + (S) * 4096 + aofs[kk][i]);   \
        stageA(XUSE, ((S) + 4) & 7);                                           \
        XUSE = *(const f32x2*)(xlp + (size_t)kn6 * 8);                         \
        __builtin_amdgcn_s_setprio(1);                                         \
        _Pragma("unroll")                                                      \
        for (int kk = 0; kk < 2; ++kk)                                         \
            _Pragma("unroll")                                                  \
            for (int i = 0; i < 4; ++i)                                        \
                _Pragma("unroll")                                              \
                for (int j = 0; j < 4; ++j)                                    \
                    acc[i][j] = __builtin_amdgcn_mfma_f32_16x16x32_bf16(       \
                        af[kk][i], BU[kk * 4 + j], acc[i][j], 0, 0, 0);        \
        __builtin_amdgcn_s_setprio(0);                                         \
        if (((S) & 3) == 3) lds_barrier();                                     \
    }

    for (int kt0 = 0; kt0 < 64; kt0 += 8) {
        GG12(kt0, 0, bfA, bfB, xu)
        GG12(kt0, 1, bfB, bfA, xv)
        GG12(kt0, 2, bfA, bfB, xu)
        GG12(kt0, 3, bfB, bfA, xv)
        GG12(kt0, 4, bfA, bfB, xu)
        GG12(kt0, 5, bfB, bfA, xv)
        GG12(kt0, 6, bfA, bfB, xu)
        GG12(kt0, 7, bfB, bfA, xv)
    }
#undef GG12

    // ---- epilogue: C/D layout col=lane&15, row=(lane>>4)*4+e ----
#pragma unroll
    for (int i = 0; i < 4; ++i) {
        const int r0 = m0 + i * 16 + lq * 4;
#pragma unroll
        for (int j = 0; j < 4; ++j) {
            const int c = n0 + wave * 64 + j * 16 + l15;
#pragma unroll
            for (int e = 0; e < 4; ++e)
                Out[(size_t)(r0 + e) * OUT_F + c] = acc[i][j][e];
        }
    }
}

// ================= fallback (ws too small for Wt) =================
#define BM 128
#define BN 128
#define BK 64
#define LDA 72
#define LDB 72

__global__ __launch_bounds__(256, 2) void gauss_gemm_fb(
        const float* __restrict__ X, const float* __restrict__ W,
        float* __restrict__ Out) {
    __shared__ __align__(16) unsigned short sA[BM * LDA];
    __shared__ __align__(16) unsigned short sB2[BN * LDB];

    const int tid  = threadIdx.x;
    const int lane = tid & 63;
    const int wave = tid >> 6;
    const int rb = blockIdx.x >> 2;
    const int cbx = blockIdx.x & 3;
    const int m0 = rb * BM;
    const int n0 = cbx * BN;
    const int wr = (wave >> 1) * 64;
    const int wc = (wave & 1) * 64;
    const int l15 = lane & 15;
    const int lq  = lane >> 4;

    f32x4 acc[4][4];
#pragma unroll
    for (int i = 0; i < 4; ++i)
#pragma unroll
        for (int j = 0; j < 4; ++j)
            acc[i][j] = (f32x4){0.f, 0.f, 0.f, 0.f};

    const int arow = tid & 127;
    const int axq  = tid >> 7;

    for (int kt = 0; kt < KTOT / BK; ++kt) {
        const int k0  = kt * BK;
        const int xc0 = kt * (BK / NG);

        const f32x4 xv = *(const f32x4*)(X + (size_t)(m0 + arow) * IN_F + xc0 + 4 * axq);
        unsigned short* sArow = sA + arow * LDA + axq * 32;
#pragma unroll
        for (int j = 0; j < 4; ++j) {
            const float xs = xv[j] * SH;
            u32x4 pk;
#pragma unroll
            for (int g = 0; g < 8; g += 2) {
                float t0 = xs + (BC0N - g * SSTEP);
                float t1 = xs + (BC0N - (g + 1) * SSTEP);
                pk[g >> 1] = pack2bf(__builtin_amdgcn_exp2f(-t0 * t0),
                                     __builtin_amdgcn_exp2f(-t1 * t1));
            }
            *(u32x4*)(sArow + j * 8) = pk;
        }

#pragma unroll
        for (int p = 0; p < 8; ++p) {
            int id = p * 256 + tid;
            int n  = id & 127;
            int k4 = id >> 7;
            const float* wp = W + (size_t)(k0 + k4 * 4) * OUT_F + n0 + n;
            u32x2 v;
            v[0] = pack2bf(wp[0], wp[OUT_F]);
            v[1] = pack2bf(wp[2 * OUT_F], wp[3 * OUT_F]);
            *(u32x2*)(sB2 + n * LDB + k4 * 4) = v;
        }

        __syncthreads();

#pragma unroll
        for (int kk = 0; kk < BK; kk += 32) {
            short8 af[4], bfv[4];
#pragma unroll
            for (int i = 0; i < 4; ++i)
                af[i] = *(const short8*)(sA + (wr + i * 16 + l15) * LDA + kk + lq * 8);
#pragma unroll
            for (int i = 0; i < 4; ++i)
                bfv[i] = *(const short8*)(sB2 + (wc + i * 16 + l15) * LDB + kk + lq * 8);
#pragma unroll
            for (int i = 0; i < 4; ++i)
#pragma unroll
                for (int j = 0; j < 4; ++j)
                    acc[i][j] = __builtin_amdgcn_mfma_f32_16x16x32_bf16(af[i], bfv[j], acc[i][j], 0, 0, 0);
        }

        __syncthreads();
    }

#pragma unroll
    for (int i = 0; i < 4; ++i) {
        const int r0 = m0 + wr + i * 16 + lq * 4;
#pragma unroll
        for (int j = 0; j < 4; ++j) {
            const int c = n0 + wc + j * 16 + l15;
#pragma unroll
            for (int e = 0; e < 4; ++e)
                Out[(size_t)(r0 + e) * OUT_F + c] = acc[i][j][e];
        }
    }
}

extern "C" void kernel_launch(void* const* d_in, const int* in_sizes, int n_in,
                              void* d_out, int out_size, void* d_ws, size_t ws_size,
                              hipStream_t stream) {
    (void)in_sizes; (void)n_in; (void)out_size;
    const float* X = (const float*)d_in[0];
    // d_in[1] = grid (constants hardcoded: linspace(-2,2,8))
    const float* W = (const float*)d_in[2];
    float* Out = (float*)d_out;

    const size_t wt_bytes = (size_t)KTOT * OUT_F * sizeof(unsigned short); // 4 MB
    if (ws_size >= wt_bytes) {
        unsigned short* Wt = (unsigned short*)d_ws;
        wt_swizzle<<<dim3(KTOT * OUT_F / 8 / 256), 256, 0, stream>>>(W, Wt);
        gauss_gemm12<<<dim3((BATCH / 64) * (OUT_F / 256)), 256, 0, stream>>>(X, Wt, Out);
    } else {
        gauss_gemm_fb<<<dim3((BATCH / BM) * (OUT_F / BN)), 256, 0, stream>>>(X, W, Out);
    }
}